// Round 1
// baseline (695.970 us; speedup 1.0000x reference)
//
#include <hip/hip_runtime.h>
#include <math.h>

#define LDIM 4096
#define CDIM 1024
#define HDIM 16
#define KDIM 64
#define SDIM 33
#define HALF_SS 16
#define MAXF 16.0f
#define MINF 1.0f
#define MAXR 256.0f

// 0.5-ulp predictors for np's fp32 transcendentals: fp64 op, one round to fp32.
__device__ __forceinline__ float sigmoid_np(float z) {
  float e = (float)exp(-(double)z);
  return __fdiv_rn(1.0f, __fadd_rn(1.0f, e));
}
__device__ __forceinline__ float silu_f(float z) {  // jax.nn order: z * sigmoid(z)
  return __fmul_rn(z, sigmoid_np(z));
}

// numpy pairwise-8 sum (8 <= n <= 128 path)
__device__ __forceinline__ float np_pairwise_sum(const float* a, int n) {
  float r[8];
#pragma unroll
  for (int j = 0; j < 8; ++j) r[j] = a[j];
  int i = 8;
  for (; i + 8 <= n; i += 8)
#pragma unroll
    for (int j = 0; j < 8; ++j) r[j] = __fadd_rn(r[j], a[i + j]);
  float res = __fadd_rn(__fadd_rn(__fadd_rn(r[0], r[1]), __fadd_rn(r[2], r[3])),
                        __fadd_rn(__fadd_rn(r[4], r[5]), __fadd_rn(r[6], r[7])));
  for (; i < n; ++i) res = __fadd_rn(res, a[i]);
  return res;
}

// ------- Kernel A: wave projection — fp64 dot (8-lane split) -> fp32 cast ----
__global__ __launch_bounds__(256) void wave_kernel(
    const float* __restrict__ x, const float* __restrict__ Ww,
    const float* __restrict__ bw, float* __restrict__ fa, float* __restrict__ pa) {
  __shared__ float xs[CDIM];
  __shared__ float wp[2 * HDIM];
  int l = blockIdx.x;
  int tid = threadIdx.x;
  const float* xrow = x + (size_t)l * CDIM;
  for (int c = tid; c < CDIM; c += 256) xs[c] = xrow[c];
  __syncthreads();
  int j = tid >> 3, sub = tid & 7;  // 32 outputs x 8 lanes, fp64 partials
  const float* wrow = Ww + j * CDIM;
  double acc = 0.0;
  for (int c = sub; c < CDIM; c += 8) acc += (double)xs[c] * (double)wrow[c];
  for (int off = 4; off; off >>= 1) acc += __shfl_down(acc, off, 8);
  if (sub == 0) {
    float v32 = (float)(acc + (double)bw[j]);  // single cast to fp32 (bw == 0)
    wp[j] = silu_f(v32);
  }
  __syncthreads();
  if (tid == 0) {
    float fv[HDIM], pv[HDIM];
    for (int h = 0; h < HDIM; ++h) {
      fv[h] = __fadd_rn(__fmul_rn(sigmoid_np(wp[h]), MAXF - MINF), MINF);
      float t32 = (float)tanh((double)wp[HDIM + h]);
      pv[h] = __fmul_rn(t32, MAXF);
    }
    fa[l] = __fdiv_rn(np_pairwise_sum(fv, HDIM), (float)HDIM);
    pa[l] = __fdiv_rn(np_pairwise_sum(pv, HDIM), (float)HDIM);
  }
}

// --- km GEMM: C = silu(fp32(A64 @ B64^T) + bias) ----------------------------
// 64x64 tile, 256 threads, acc 8x2 fp64/thread. Grid 1024 blocks = 4/CU.
// Register-prefetch double-buffered LDS, one barrier per K-step.
// Per-output arithmetic bit-identical to previous version: same fp64 products,
// same k-ascending accumulation chain, single fp64->fp32 cast, then silu.
// LDS rows padded to 66 doubles (528B = 33*16): b128 alignment kept, staging
// write conflicts 4-way -> 2-way (free). B-fragment read is a lane-linear
// 512B sweep (conflict-free); A-fragment read is broadcast (free).
__global__ __launch_bounds__(256) void gemm_bt_silu_f64(
    const float* __restrict__ A, const float* __restrict__ B,
    const float* __restrict__ bias, float* __restrict__ Cout,
    int M, int N, int Kd) {
  __shared__ double Asd[2][16][66];  // 16.5 KB
  __shared__ double Bsd[2][16][66];  // 16.5 KB
  int tid = threadIdx.x;
  int tx = tid & 31;   // n-dir: 2 cols each
  int ty = tid >> 5;   // m-dir: 8 rows each
  int m0 = blockIdx.y * 64, n0 = blockIdx.x * 64;

  // staging map: 4 lanes per row, each holds 4 consecutive k (float4)
  int rS = tid >> 2;            // 0..63 (row within tile)
  int kq = (tid & 3) * 4;       // 0,4,8,12
  const float* Ag = A + (size_t)(m0 + rS) * Kd + kq;
  const float* Bg = B + (size_t)(n0 + rS) * Kd + kq;

  double acc[8][2] = {};

  // prologue: stage k-tile 0 into buffer 0
  {
    float4 va = *(const float4*)(Ag);
    float4 vb = *(const float4*)(Bg);
    Asd[0][kq + 0][rS] = (double)va.x; Asd[0][kq + 1][rS] = (double)va.y;
    Asd[0][kq + 2][rS] = (double)va.z; Asd[0][kq + 3][rS] = (double)va.w;
    Bsd[0][kq + 0][rS] = (double)vb.x; Bsd[0][kq + 1][rS] = (double)vb.y;
    Bsd[0][kq + 2][rS] = (double)vb.z; Bsd[0][kq + 3][rS] = (double)vb.w;
  }
  __syncthreads();

  const int NK = Kd >> 4;  // 64 k-steps of 16
  for (int kt = 0; kt < NK; ++kt) {
    int cur = kt & 1;
    float4 va, vb;
    bool pf = (kt + 1 < NK);
    if (pf) {  // issue next-tile global loads before compute (latency hides)
      va = *(const float4*)(Ag + (kt + 1) * 16);
      vb = *(const float4*)(Bg + (kt + 1) * 16);
    }
#pragma unroll
    for (int kk = 0; kk < 16; ++kk) {
      const double2* ap = (const double2*)&Asd[cur][kk][ty * 8];
      double2 a0 = ap[0], a1 = ap[1], a2 = ap[2], a3 = ap[3];
      double2 bv = *(const double2*)&Bsd[cur][kk][tx * 2];
      double a[8] = {a0.x, a0.y, a1.x, a1.y, a2.x, a2.y, a3.x, a3.y};
#pragma unroll
      for (int i = 0; i < 8; ++i) {
        acc[i][0] += a[i] * bv.x;  // v_fma_f64, k-ascending chain
        acc[i][1] += a[i] * bv.y;
      }
    }
    if (pf) {  // write next tile into the other buffer (safe: last reader of
               // that buffer finished before previous barrier)
      int nxt = cur ^ 1;
      Asd[nxt][kq + 0][rS] = (double)va.x; Asd[nxt][kq + 1][rS] = (double)va.y;
      Asd[nxt][kq + 2][rS] = (double)va.z; Asd[nxt][kq + 3][rS] = (double)va.w;
      Bsd[nxt][kq + 0][rS] = (double)vb.x; Bsd[nxt][kq + 1][rS] = (double)vb.y;
      Bsd[nxt][kq + 2][rS] = (double)vb.z; Bsd[nxt][kq + 3][rS] = (double)vb.w;
    }
    __syncthreads();
  }

#pragma unroll
  for (int i = 0; i < 8; ++i) {
    int mm = m0 + ty * 8 + i;
    int nn = n0 + tx * 2;
    float v0 = (float)acc[i][0];            // fp64 dot -> one fp32 cast
    v0 = __fadd_rn(v0, bias[nn]);           // bias == 0
    float v1 = (float)acc[i][1];
    v1 = __fadd_rn(v1, bias[nn + 1]);
    float2 o;
    o.x = silu_f(v0);
    o.y = silu_f(v1);
    *(float2*)&Cout[(size_t)mm * N + nn] = o;
  }
}

// --- out GEMM: fp32 accumulate; 64x64 tile, 4x4 acc/thread ------------------
// Grid 1024 blocks = 4/CU (was 256 = 1/CU). Same double-buffer structure.
// Per-element k-order identical to previous version (sequential fmac chain).
__global__ __launch_bounds__(256) void gemm_bt_silu_f32(
    const float* __restrict__ A, const float* __restrict__ B,
    float* __restrict__ Cout, int M, int N, int Kd) {
  __shared__ float Asf[2][16][68];  // rows 272B = 17*16: b128-aligned
  __shared__ float Bsf[2][16][68];
  int tid = threadIdx.x;
  int tx = tid & 15;   // n-dir: 4 cols each
  int ty = tid >> 4;   // m-dir: 4 rows each
  int m0 = blockIdx.y * 64, n0 = blockIdx.x * 64;

  int rS = tid >> 2;
  int kq = (tid & 3) * 4;
  const float* Ag = A + (size_t)(m0 + rS) * Kd + kq;
  const float* Bg = B + (size_t)(n0 + rS) * Kd + kq;

  float acc[4][4] = {};

  {
    float4 va = *(const float4*)(Ag);
    float4 vb = *(const float4*)(Bg);
    Asf[0][kq + 0][rS] = va.x; Asf[0][kq + 1][rS] = va.y;
    Asf[0][kq + 2][rS] = va.z; Asf[0][kq + 3][rS] = va.w;
    Bsf[0][kq + 0][rS] = vb.x; Bsf[0][kq + 1][rS] = vb.y;
    Bsf[0][kq + 2][rS] = vb.z; Bsf[0][kq + 3][rS] = vb.w;
  }
  __syncthreads();

  const int NK = Kd >> 4;
  for (int kt = 0; kt < NK; ++kt) {
    int cur = kt & 1;
    float4 va, vb;
    bool pf = (kt + 1 < NK);
    if (pf) {
      va = *(const float4*)(Ag + (kt + 1) * 16);
      vb = *(const float4*)(Bg + (kt + 1) * 16);
    }
#pragma unroll
    for (int kk = 0; kk < 16; ++kk) {
      float4 af = *(const float4*)&Asf[cur][kk][ty * 4];
      float4 bf = *(const float4*)&Bsf[cur][kk][tx * 4];
      float a[4] = {af.x, af.y, af.z, af.w};
      float b[4] = {bf.x, bf.y, bf.z, bf.w};
#pragma unroll
      for (int i = 0; i < 4; ++i)
#pragma unroll
        for (int j2 = 0; j2 < 4; ++j2) acc[i][j2] += a[i] * b[j2];  // fp32 fmac
    }
    if (pf) {
      int nxt = cur ^ 1;
      Asf[nxt][kq + 0][rS] = va.x; Asf[nxt][kq + 1][rS] = va.y;
      Asf[nxt][kq + 2][rS] = va.z; Asf[nxt][kq + 3][rS] = va.w;
      Bsf[nxt][kq + 0][rS] = vb.x; Bsf[nxt][kq + 1][rS] = vb.y;
      Bsf[nxt][kq + 2][rS] = vb.z; Bsf[nxt][kq + 3][rS] = vb.w;
    }
    __syncthreads();
  }

#pragma unroll
  for (int i = 0; i < 4; ++i) {
    int mm = m0 + ty * 4 + i;
    int nn = n0 + tx * 4;
    float4 o;
    o.x = silu_f(acc[i][0]);
    o.y = silu_f(acc[i][1]);
    o.z = silu_f(acc[i][2]);
    o.w = silu_f(acc[i][3]);
    *(float4*)&Cout[(size_t)mm * N + nn] = o;
  }
}

// ---------------- Kernel C: fp32 chain — byte-identical to R10..R12 ----------
__global__ __launch_bounds__(256) void conv_kernel(
    const float* __restrict__ x, const float* __restrict__ km,
    const float* __restrict__ fa, const float* __restrict__ pa,
    float* __restrict__ conv) {
  int l = blockIdx.x;
  int tid = threadIdx.x;
  __shared__ int s_idx[SDIM];
  __shared__ int s_ifl[SDIM];
  __shared__ float s_wc[SDIM];
  __shared__ float s_val[SDIM];
  __shared__ float kern[HDIM][SDIM];
  __shared__ float s_den[HDIM];
  if (tid < SDIM) {
    float f = fa[l], p = pa[l];
    float rel = __fadd_rn(__fmul_rn((float)(tid - HALF_SS), f), p);
    float pos = __fadd_rn((float)l, rel);
    bool valid = (pos >= 0.f) && (pos < (float)LDIM);
    int idx = (int)pos;                       // trunc toward zero
    idx = min(max(idx, 0), LDIM - 1);
    s_idx[tid] = idx;
    s_val[tid] = valid ? 1.f : 0.f;
    float np_ = __fdiv_rn(__fadd_rn(rel, MAXR), 2.f * MAXR);
    np_ = fminf(fmaxf(np_, 0.f), 1.f);
    float idxf = __fmul_rn(np_, (float)(KDIM - 1));
    int ifl = (int)idxf;
    ifl = min(max(ifl, 0), KDIM - 2);
    s_ifl[tid] = ifl;
    s_wc[tid] = __fsub_rn(idxf, (float)ifl);
  }
  __syncthreads();
  for (int t = tid; t < HDIM * SDIM; t += 256) {
    int h = t / SDIM, s = t - h * SDIM;
    const float* kb = km + (size_t)l * CDIM + h * KDIM;
    float wc = s_wc[s];
    float wf = __fsub_rn(1.f, wc);
    float v = __fadd_rn(__fmul_rn(kb[s_ifl[s]], wf), __fmul_rn(kb[s_ifl[s] + 1], wc));
    kern[h][s] = __fmul_rn(v, s_val[s]);
  }
  __syncthreads();
  if (tid < HDIM) {
    float sum = np_pairwise_sum(&kern[tid][0], SDIM);
    s_den[tid] = __fadd_rn(sum, 1e-8f);
  }
  __syncthreads();
  for (int t = tid; t < HDIM * SDIM; t += 256) {
    int h = t / SDIM, s = t - h * SDIM;
    kern[h][s] = __fdiv_rn(kern[h][s], s_den[h]);
  }
  __syncthreads();
  float acc[4] = {0.f, 0.f, 0.f, 0.f};
  for (int s = 0; s < SDIM; ++s) {
    const float* xr = x + (size_t)s_idx[s] * CDIM;
#pragma unroll
    for (int q = 0; q < 4; ++q) {
      int c = tid + q * 256;
      acc[q] = __fadd_rn(acc[q], __fmul_rn(xr[c], kern[c >> 6][s]));
    }
  }
#pragma unroll
  for (int q = 0; q < 4; ++q) {
    int c = tid + q * 256;
    conv[(size_t)l * CDIM + c] = acc[q];
  }
}

extern "C" void kernel_launch(void* const* d_in, const int* in_sizes, int n_in,
                              void* d_out, int out_size, void* d_ws, size_t ws_size,
                              hipStream_t stream) {
  const float* x  = (const float*)d_in[0];
  const float* Ww = (const float*)d_in[1];
  const float* bw = (const float*)d_in[2];
  const float* Wk = (const float*)d_in[3];
  const float* bk = (const float*)d_in[4];
  const float* Wo = (const float*)d_in[5];
  float* out = (float*)d_out;

  float* fa   = (float*)d_ws;
  float* pa   = fa + LDIM;
  float* km   = pa + LDIM;                   // 16 MB
  float* conv = km + (size_t)LDIM * CDIM;    // 16 MB

  wave_kernel<<<LDIM, 256, 0, stream>>>(x, Ww, bw, fa, pa);

  dim3 kmgrid(CDIM / 64, LDIM / 64);         // 16 x 64 = 1024 blocks (4/CU)
  gemm_bt_silu_f64<<<kmgrid, 256, 0, stream>>>(x, Wk, bk, km, LDIM, CDIM, CDIM);

  conv_kernel<<<LDIM, 256, 0, stream>>>(x, km, fa, pa, conv);

  dim3 ogrid(CDIM / 64, LDIM / 64);          // 16 x 64 = 1024 blocks (4/CU)
  gemm_bt_silu_f32<<<ogrid, 256, 0, stream>>>(conv, Wo, out, LDIM, CDIM, CDIM);
}

// Round 2
// 542.711 us; speedup vs baseline: 1.2824x; 1.2824x over previous
//
#include <hip/hip_runtime.h>
#include <math.h>

#define LDIM 4096
#define CDIM 1024
#define HDIM 16
#define KDIM 64
#define SDIM 33
#define HALF_SS 16
#define MAXF 16.0f
#define MINF 1.0f
#define MAXR 256.0f

// 0.5-ulp predictors for np's fp32 transcendentals: fp64 op, one round to fp32.
__device__ __forceinline__ float sigmoid_np(float z) {
  float e = (float)exp(-(double)z);
  return __fdiv_rn(1.0f, __fadd_rn(1.0f, e));
}
__device__ __forceinline__ float silu_f(float z) {  // jax.nn order: z * sigmoid(z)
  return __fmul_rn(z, sigmoid_np(z));
}

// numpy pairwise-8 sum (8 <= n <= 128 path)
__device__ __forceinline__ float np_pairwise_sum(const float* a, int n) {
  float r[8];
#pragma unroll
  for (int j = 0; j < 8; ++j) r[j] = a[j];
  int i = 8;
  for (; i + 8 <= n; i += 8)
#pragma unroll
    for (int j = 0; j < 8; ++j) r[j] = __fadd_rn(r[j], a[i + j]);
  float res = __fadd_rn(__fadd_rn(__fadd_rn(r[0], r[1]), __fadd_rn(r[2], r[3])),
                        __fadd_rn(__fadd_rn(r[4], r[5]), __fadd_rn(r[6], r[7])));
  for (; i < n; ++i) res = __fadd_rn(res, a[i]);
  return res;
}

// ------- Kernel A: wave projection — fp64 dot (8-lane split) -> fp32 cast ----
__global__ __launch_bounds__(256) void wave_kernel(
    const float* __restrict__ x, const float* __restrict__ Ww,
    const float* __restrict__ bw, float* __restrict__ fa, float* __restrict__ pa) {
  __shared__ float xs[CDIM];
  __shared__ float wp[2 * HDIM];
  int l = blockIdx.x;
  int tid = threadIdx.x;
  const float* xrow = x + (size_t)l * CDIM;
  for (int c = tid; c < CDIM; c += 256) xs[c] = xrow[c];
  __syncthreads();
  int j = tid >> 3, sub = tid & 7;  // 32 outputs x 8 lanes, fp64 partials
  const float* wrow = Ww + j * CDIM;
  double acc = 0.0;
  for (int c = sub; c < CDIM; c += 8) acc += (double)xs[c] * (double)wrow[c];
  for (int off = 4; off; off >>= 1) acc += __shfl_down(acc, off, 8);
  if (sub == 0) {
    float v32 = (float)(acc + (double)bw[j]);  // single cast to fp32 (bw == 0)
    wp[j] = silu_f(v32);
  }
  __syncthreads();
  if (tid == 0) {
    float fv[HDIM], pv[HDIM];
    for (int h = 0; h < HDIM; ++h) {
      fv[h] = __fadd_rn(__fmul_rn(sigmoid_np(wp[h]), MAXF - MINF), MINF);
      float t32 = (float)tanh((double)wp[HDIM + h]);
      pv[h] = __fmul_rn(t32, MAXF);
    }
    fa[l] = __fdiv_rn(np_pairwise_sum(fv, HDIM), (float)HDIM);
    pa[l] = __fdiv_rn(np_pairwise_sum(pv, HDIM), (float)HDIM);
  }
}

// --- km GEMM: C = silu(fp32(A64 @ B64^T) + bias) ----------------------------
// Round-0 skeleton (128x64 tile, 256 thr, acc 8x4 fp64, single-buffered) with
// bank-conflict engineering + BK=32 (half the barriers). Bit-identical math:
// same fp64 products, same k-ascending chain per output, single fp32 cast.
//   * B-read:  thread owns cols {tx+16j} -> 16 unique b64 addrs contiguous
//              128B  -> all 32 banks exactly once -> conflict-free (was 4-way).
//   * A-read:  4 unique addrs/wave (ty 0..3), broadcast -> free.
//   * Pads:    A rows 129 doubles (stride == 2 banks mod 32), B rows 65 ->
//              staging-write kq-groups spread -> ~2-way (free) on most writes.
__global__ __launch_bounds__(256) void gemm_bt_silu_f64(
    const float* __restrict__ A, const float* __restrict__ B,
    const float* __restrict__ bias, float* __restrict__ Cout,
    int M, int N, int Kd) {
  __shared__ double Asd[32][129];  // 33.0 KB, row 1032B (stride 258 banks = 2 mod 32)
  __shared__ double Bsd[32][65];   // 16.6 KB, row  520B (stride 130 banks = 2 mod 32)
  int tid = threadIdx.x;
  int tx = tid & 15;   // n-dir: cols tx + 16*j, j=0..3
  int ty = tid >> 4;   // m-dir: rows ty*8 .. ty*8+7
  int m0 = blockIdx.y * 128, n0 = blockIdx.x * 64;
  double acc[8][4] = {};
  for (int kt = 0; kt < Kd; kt += 32) {
    // stage A: 128 rows x 32 k; 4 float4/thread, cvt to double once
#pragma unroll
    for (int q = 0; q < 4; ++q) {
      int e = tid + 256 * q;
      int row = e >> 3, kq = (e & 7) * 4;
      float4 va = *(const float4*)(A + (size_t)(m0 + row) * Kd + kt + kq);
      Asd[kq + 0][row] = (double)va.x; Asd[kq + 1][row] = (double)va.y;
      Asd[kq + 2][row] = (double)va.z; Asd[kq + 3][row] = (double)va.w;
    }
    // stage B: 64 rows x 32 k; 2 float4/thread
#pragma unroll
    for (int q = 0; q < 2; ++q) {
      int e = tid + 256 * q;
      int row = e >> 3, kq = (e & 7) * 4;
      float4 vb = *(const float4*)(B + (size_t)(n0 + row) * Kd + kt + kq);
      Bsd[kq + 0][row] = (double)vb.x; Bsd[kq + 1][row] = (double)vb.y;
      Bsd[kq + 2][row] = (double)vb.z; Bsd[kq + 3][row] = (double)vb.w;
    }
    __syncthreads();
#pragma unroll
    for (int kk = 0; kk < 32; ++kk) {
      double a[8], b[4];
#pragma unroll
      for (int i = 0; i < 8; ++i) a[i] = Asd[kk][ty * 8 + i];
#pragma unroll
      for (int j2 = 0; j2 < 4; ++j2) b[j2] = Bsd[kk][tx + 16 * j2];
#pragma unroll
      for (int i = 0; i < 8; ++i)
#pragma unroll
        for (int j2 = 0; j2 < 4; ++j2) acc[i][j2] += a[i] * b[j2];  // v_fma_f64
    }
    __syncthreads();
  }
#pragma unroll
  for (int i = 0; i < 8; ++i) {
    int mm = m0 + ty * 8 + i;
#pragma unroll
    for (int j2 = 0; j2 < 4; ++j2) {
      int nn = n0 + tx + 16 * j2;
      float v32 = (float)acc[i][j2];     // fp64 dot -> one fp32 cast
      v32 = __fadd_rn(v32, bias[nn]);    // bias == 0
      Cout[(size_t)mm * N + nn] = silu_f(v32);
    }
  }
}

// --- out GEMM: fp32 accumulate; 128x64 tile, 8x4 acc/thread -----------------
// Grid 512 blocks = 2/CU (was 256 = 1/CU). Per-element k-order identical to
// round-0 (single sequential fmac chain, k ascending). Conflict engineering:
//   * B-read:  cols {tx+16j} -> 16 unique b32 addrs contiguous 64B -> free.
//   * A-read:  float4 at ty*8 (ty 0..3/wave) -> 4 unique addrs -> free.
//   * Pads:    A rows 132 floats (16B-aligned rows, writes 2-way=free),
//              B rows 66 floats (writes conflict-free).
__global__ __launch_bounds__(256) void gemm_bt_silu_f32(
    const float* __restrict__ A, const float* __restrict__ B,
    float* __restrict__ Cout, int M, int N, int Kd) {
  __shared__ float Asf[16][132];  // row 528B, 16B-aligned
  __shared__ float Bsf[16][66];   // row 264B
  int tid = threadIdx.x;
  int tx = tid & 15;   // n-dir: cols tx + 16*j
  int ty = tid >> 4;   // m-dir: rows ty*8 .. ty*8+7
  int m0 = blockIdx.y * 128, n0 = blockIdx.x * 64;
  float acc[8][4] = {};
  for (int kt = 0; kt < Kd; kt += 16) {
    // stage A: 128 rows x 16 k; 2 float4/thread
#pragma unroll
    for (int q = 0; q < 2; ++q) {
      int e = tid + 256 * q;
      int row = e >> 2, kq = (e & 3) * 4;
      float4 va = *(const float4*)(A + (size_t)(m0 + row) * Kd + kt + kq);
      Asf[kq + 0][row] = va.x; Asf[kq + 1][row] = va.y;
      Asf[kq + 2][row] = va.z; Asf[kq + 3][row] = va.w;
    }
    // stage B: 64 rows x 16 k; 1 float4/thread
    {
      int row = tid >> 2, kq = (tid & 3) * 4;
      float4 vb = *(const float4*)(B + (size_t)(n0 + row) * Kd + kt + kq);
      Bsf[kq + 0][row] = vb.x; Bsf[kq + 1][row] = vb.y;
      Bsf[kq + 2][row] = vb.z; Bsf[kq + 3][row] = vb.w;
    }
    __syncthreads();
#pragma unroll
    for (int kk = 0; kk < 16; ++kk) {
      float4 a0 = *(const float4*)&Asf[kk][ty * 8];
      float4 a1 = *(const float4*)&Asf[kk][ty * 8 + 4];
      float a[8] = {a0.x, a0.y, a0.z, a0.w, a1.x, a1.y, a1.z, a1.w};
      float b[4];
#pragma unroll
      for (int j2 = 0; j2 < 4; ++j2) b[j2] = Bsf[kk][tx + 16 * j2];
#pragma unroll
      for (int i = 0; i < 8; ++i)
#pragma unroll
        for (int j2 = 0; j2 < 4; ++j2) acc[i][j2] += a[i] * b[j2];  // fp32 fmac
    }
    __syncthreads();
  }
#pragma unroll
  for (int i = 0; i < 8; ++i) {
    int mm = m0 + ty * 8 + i;
#pragma unroll
    for (int j2 = 0; j2 < 4; ++j2) {
      int nn = n0 + tx + 16 * j2;
      Cout[(size_t)mm * N + nn] = silu_f(acc[i][j2]);
    }
  }
}

// ---------------- Kernel C: fp32 chain — byte-identical to R10..R12 ----------
__global__ __launch_bounds__(256) void conv_kernel(
    const float* __restrict__ x, const float* __restrict__ km,
    const float* __restrict__ fa, const float* __restrict__ pa,
    float* __restrict__ conv) {
  int l = blockIdx.x;
  int tid = threadIdx.x;
  __shared__ int s_idx[SDIM];
  __shared__ int s_ifl[SDIM];
  __shared__ float s_wc[SDIM];
  __shared__ float s_val[SDIM];
  __shared__ float kern[HDIM][SDIM];
  __shared__ float s_den[HDIM];
  if (tid < SDIM) {
    float f = fa[l], p = pa[l];
    float rel = __fadd_rn(__fmul_rn((float)(tid - HALF_SS), f), p);
    float pos = __fadd_rn((float)l, rel);
    bool valid = (pos >= 0.f) && (pos < (float)LDIM);
    int idx = (int)pos;                       // trunc toward zero
    idx = min(max(idx, 0), LDIM - 1);
    s_idx[tid] = idx;
    s_val[tid] = valid ? 1.f : 0.f;
    float np_ = __fdiv_rn(__fadd_rn(rel, MAXR), 2.f * MAXR);
    np_ = fminf(fmaxf(np_, 0.f), 1.f);
    float idxf = __fmul_rn(np_, (float)(KDIM - 1));
    int ifl = (int)idxf;
    ifl = min(max(ifl, 0), KDIM - 2);
    s_ifl[tid] = ifl;
    s_wc[tid] = __fsub_rn(idxf, (float)ifl);
  }
  __syncthreads();
  for (int t = tid; t < HDIM * SDIM; t += 256) {
    int h = t / SDIM, s = t - h * SDIM;
    const float* kb = km + (size_t)l * CDIM + h * KDIM;
    float wc = s_wc[s];
    float wf = __fsub_rn(1.f, wc);
    float v = __fadd_rn(__fmul_rn(kb[s_ifl[s]], wf), __fmul_rn(kb[s_ifl[s] + 1], wc));
    kern[h][s] = __fmul_rn(v, s_val[s]);
  }
  __syncthreads();
  if (tid < HDIM) {
    float sum = np_pairwise_sum(&kern[tid][0], SDIM);
    s_den[tid] = __fadd_rn(sum, 1e-8f);
  }
  __syncthreads();
  for (int t = tid; t < HDIM * SDIM; t += 256) {
    int h = t / SDIM, s = t - h * SDIM;
    kern[h][s] = __fdiv_rn(kern[h][s], s_den[h]);
  }
  __syncthreads();
  float acc[4] = {0.f, 0.f, 0.f, 0.f};
  for (int s = 0; s < SDIM; ++s) {
    const float* xr = x + (size_t)s_idx[s] * CDIM;
#pragma unroll
    for (int q = 0; q < 4; ++q) {
      int c = tid + q * 256;
      acc[q] = __fadd_rn(acc[q], __fmul_rn(xr[c], kern[c >> 6][s]));
    }
  }
#pragma unroll
  for (int q = 0; q < 4; ++q) {
    int c = tid + q * 256;
    conv[(size_t)l * CDIM + c] = acc[q];
  }
}

extern "C" void kernel_launch(void* const* d_in, const int* in_sizes, int n_in,
                              void* d_out, int out_size, void* d_ws, size_t ws_size,
                              hipStream_t stream) {
  const float* x  = (const float*)d_in[0];
  const float* Ww = (const float*)d_in[1];
  const float* bw = (const float*)d_in[2];
  const float* Wk = (const float*)d_in[3];
  const float* bk = (const float*)d_in[4];
  const float* Wo = (const float*)d_in[5];
  float* out = (float*)d_out;

  float* fa   = (float*)d_ws;
  float* pa   = fa + LDIM;
  float* km   = pa + LDIM;                   // 16 MB
  float* conv = km + (size_t)LDIM * CDIM;    // 16 MB

  wave_kernel<<<LDIM, 256, 0, stream>>>(x, Ww, bw, fa, pa);

  dim3 kmgrid(CDIM / 64, LDIM / 128);        // 16 x 32 = 512 blocks (2/CU)
  gemm_bt_silu_f64<<<kmgrid, 256, 0, stream>>>(x, Wk, bk, km, LDIM, CDIM, CDIM);

  conv_kernel<<<LDIM, 256, 0, stream>>>(x, km, fa, pa, conv);

  dim3 ogrid(CDIM / 64, LDIM / 128);         // 16 x 32 = 512 blocks (2/CU)
  gemm_bt_silu_f32<<<ogrid, 256, 0, stream>>>(conv, Wo, out, LDIM, CDIM, CDIM);
}

// Round 3
// 539.449 us; speedup vs baseline: 1.2902x; 1.0060x over previous
//
#include <hip/hip_runtime.h>
#include <math.h>

#define LDIM 4096
#define CDIM 1024
#define HDIM 16
#define KDIM 64
#define SDIM 33
#define HALF_SS 16
#define MAXF 16.0f
#define MINF 1.0f
#define MAXR 256.0f

// 0.5-ulp predictors for np's fp32 transcendentals: fp64 op, one round to fp32.
__device__ __forceinline__ float sigmoid_np(float z) {
  float e = (float)exp(-(double)z);
  return __fdiv_rn(1.0f, __fadd_rn(1.0f, e));
}
__device__ __forceinline__ float silu_f(float z) {  // jax.nn order: z * sigmoid(z)
  return __fmul_rn(z, sigmoid_np(z));
}

// numpy pairwise-8 sum (8 <= n <= 128 path)
__device__ __forceinline__ float np_pairwise_sum(const float* a, int n) {
  float r[8];
#pragma unroll
  for (int j = 0; j < 8; ++j) r[j] = a[j];
  int i = 8;
  for (; i + 8 <= n; i += 8)
#pragma unroll
    for (int j = 0; j < 8; ++j) r[j] = __fadd_rn(r[j], a[i + j]);
  float res = __fadd_rn(__fadd_rn(__fadd_rn(r[0], r[1]), __fadd_rn(r[2], r[3])),
                        __fadd_rn(__fadd_rn(r[4], r[5]), __fadd_rn(r[6], r[7])));
  for (; i < n; ++i) res = __fadd_rn(res, a[i]);
  return res;
}

// ------- Kernel A: wave projection — fp64 dot (8-lane split) -> fp32 cast ----
__global__ __launch_bounds__(256) void wave_kernel(
    const float* __restrict__ x, const float* __restrict__ Ww,
    const float* __restrict__ bw, float* __restrict__ fa, float* __restrict__ pa) {
  __shared__ float xs[CDIM];
  __shared__ float wp[2 * HDIM];
  int l = blockIdx.x;
  int tid = threadIdx.x;
  const float* xrow = x + (size_t)l * CDIM;
  for (int c = tid; c < CDIM; c += 256) xs[c] = xrow[c];
  __syncthreads();
  int j = tid >> 3, sub = tid & 7;  // 32 outputs x 8 lanes, fp64 partials
  const float* wrow = Ww + j * CDIM;
  double acc = 0.0;
  for (int c = sub; c < CDIM; c += 8) acc += (double)xs[c] * (double)wrow[c];
  for (int off = 4; off; off >>= 1) acc += __shfl_down(acc, off, 8);
  if (sub == 0) {
    float v32 = (float)(acc + (double)bw[j]);  // single cast to fp32 (bw == 0)
    wp[j] = silu_f(v32);
  }
  __syncthreads();
  if (tid == 0) {
    float fv[HDIM], pv[HDIM];
    for (int h = 0; h < HDIM; ++h) {
      fv[h] = __fadd_rn(__fmul_rn(sigmoid_np(wp[h]), MAXF - MINF), MINF);
      float t32 = (float)tanh((double)wp[HDIM + h]);
      pv[h] = __fmul_rn(t32, MAXF);
    }
    fa[l] = __fdiv_rn(np_pairwise_sum(fv, HDIM), (float)HDIM);
    pa[l] = __fdiv_rn(np_pairwise_sum(pv, HDIM), (float)HDIM);
  }
}

// --- km GEMM: C = silu(fp32(A64 @ B64^T) + bias) ----------------------------
// 128x64 tile, 256 thr, acc 8x4 fp64, BK=32, single-buffered.
// LDS-read engineering: 6x ds_read_b128 per kk per lane (round-0 width) AND
// conflict-free (round-2's mistake was scalar b64 reads from misaligned pads):
//   * A rows 130 dbl (1040B = 65*16: every row 16B-aligned -> b128 legal).
//     A-read: 4x b128, 4 unique addrs/wave (broadcast), 2-way bank = free.
//   * B rows 68 dbl (544B = 34*16). Thread's cols {2tx,2tx+1,2tx+32,2tx+33}:
//     2x double2 (b128) at 16B-aligned addrs; 16 consecutive granules ->
//     every bank hit exactly 2x = free (m136).
// Bit-identical math: same fp64 products, same k-ascending chain per output,
// single fp64->fp32 cast; only the thread<->column assignment changed.
__global__ __launch_bounds__(256) void gemm_bt_silu_f64(
    const float* __restrict__ A, const float* __restrict__ B,
    const float* __restrict__ bias, float* __restrict__ Cout,
    int M, int N, int Kd) {
  __shared__ double Asd[32][130];  // 33.3 KB
  __shared__ double Bsd[32][68];   // 17.4 KB
  int tid = threadIdx.x;
  int tx = tid & 15;   // n-dir: cols 2tx,2tx+1,2tx+32,2tx+33
  int ty = tid >> 4;   // m-dir: rows ty*8 .. ty*8+7
  int m0 = blockIdx.y * 128, n0 = blockIdx.x * 64;
  double acc[8][4] = {};
  for (int kt = 0; kt < Kd; kt += 32) {
    // stage A: 128 rows x 32 k; 4 float4/thread, cvt to double once
#pragma unroll
    for (int q = 0; q < 4; ++q) {
      int e = tid + 256 * q;
      int row = e >> 3, kq = (e & 7) * 4;
      float4 va = *(const float4*)(A + (size_t)(m0 + row) * Kd + kt + kq);
      Asd[kq + 0][row] = (double)va.x; Asd[kq + 1][row] = (double)va.y;
      Asd[kq + 2][row] = (double)va.z; Asd[kq + 3][row] = (double)va.w;
    }
    // stage B: 64 rows x 32 k; 2 float4/thread
#pragma unroll
    for (int q = 0; q < 2; ++q) {
      int e = tid + 256 * q;
      int row = e >> 3, kq = (e & 7) * 4;
      float4 vb = *(const float4*)(B + (size_t)(n0 + row) * Kd + kt + kq);
      Bsd[kq + 0][row] = (double)vb.x; Bsd[kq + 1][row] = (double)vb.y;
      Bsd[kq + 2][row] = (double)vb.z; Bsd[kq + 3][row] = (double)vb.w;
    }
    __syncthreads();
#pragma unroll
    for (int kk = 0; kk < 32; ++kk) {
      const double2* ap = (const double2*)&Asd[kk][ty * 8];   // 16B-aligned
      double2 a0 = ap[0], a1 = ap[1], a2 = ap[2], a3 = ap[3]; // 4x b128
      double2 b01 = *(const double2*)&Bsd[kk][2 * tx];        // b128
      double2 b23 = *(const double2*)&Bsd[kk][2 * tx + 32];   // b128
      double a[8] = {a0.x, a0.y, a1.x, a1.y, a2.x, a2.y, a3.x, a3.y};
#pragma unroll
      for (int i = 0; i < 8; ++i) {
        acc[i][0] += a[i] * b01.x;  // v_fma_f64, k-ascending chain
        acc[i][1] += a[i] * b01.y;
        acc[i][2] += a[i] * b23.x;
        acc[i][3] += a[i] * b23.y;
      }
    }
    __syncthreads();
  }
#pragma unroll
  for (int i = 0; i < 8; ++i) {
    int mm = m0 + ty * 8 + i;
    size_t rowoff = (size_t)mm * N + n0;
#pragma unroll
    for (int half = 0; half < 2; ++half) {
      int nn = 2 * tx + half * 32;
      float v0 = (float)acc[i][half * 2 + 0];  // fp64 dot -> one fp32 cast
      v0 = __fadd_rn(v0, bias[n0 + nn]);       // bias == 0
      float v1 = (float)acc[i][half * 2 + 1];
      v1 = __fadd_rn(v1, bias[n0 + nn + 1]);
      float2 o;
      o.x = silu_f(v0);
      o.y = silu_f(v1);
      *(float2*)&Cout[rowoff + nn] = o;
    }
  }
}

// --- out GEMM: fp32 accumulate; 128x64 tile, 8x4 acc/thread, BK=32 ----------
// Grid 512 blocks = 2/CU. Per-output k-order identical (sequential fmac chain,
// k ascending). Same read-width + conflict engineering as the f64 kernel:
//   * A rows 132 fl (528B = 33*16, aligned): 2x b128 broadcast reads, free.
//   * B rows 68 fl (272B = 17*16): cols {2tx,2tx+1,2tx+32,2tx+33} -> 2x b64,
//     16 addrs stride 2 banks -> all 32 banks exactly once = conflict-free.
__global__ __launch_bounds__(256) void gemm_bt_silu_f32(
    const float* __restrict__ A, const float* __restrict__ B,
    float* __restrict__ Cout, int M, int N, int Kd) {
  __shared__ float Asf[32][132];  // 16.9 KB
  __shared__ float Bsf[32][68];   // 8.7 KB
  int tid = threadIdx.x;
  int tx = tid & 15;   // n-dir: cols 2tx,2tx+1,2tx+32,2tx+33
  int ty = tid >> 4;   // m-dir: rows ty*8 .. ty*8+7
  int m0 = blockIdx.y * 128, n0 = blockIdx.x * 64;
  float acc[8][4] = {};
  for (int kt = 0; kt < Kd; kt += 32) {
    // stage A: 128 rows x 32 k; 4 float4/thread
#pragma unroll
    for (int q = 0; q < 4; ++q) {
      int e = tid + 256 * q;
      int row = e >> 3, kq = (e & 7) * 4;
      float4 va = *(const float4*)(A + (size_t)(m0 + row) * Kd + kt + kq);
      Asf[kq + 0][row] = va.x; Asf[kq + 1][row] = va.y;
      Asf[kq + 2][row] = va.z; Asf[kq + 3][row] = va.w;
    }
    // stage B: 64 rows x 32 k; 2 float4/thread
#pragma unroll
    for (int q = 0; q < 2; ++q) {
      int e = tid + 256 * q;
      int row = e >> 3, kq = (e & 7) * 4;
      float4 vb = *(const float4*)(B + (size_t)(n0 + row) * Kd + kt + kq);
      Bsf[kq + 0][row] = vb.x; Bsf[kq + 1][row] = vb.y;
      Bsf[kq + 2][row] = vb.z; Bsf[kq + 3][row] = vb.w;
    }
    __syncthreads();
#pragma unroll
    for (int kk = 0; kk < 32; ++kk) {
      float4 a0 = *(const float4*)&Asf[kk][ty * 8];      // b128
      float4 a1 = *(const float4*)&Asf[kk][ty * 8 + 4];  // b128
      float2 b01 = *(const float2*)&Bsf[kk][2 * tx];       // b64
      float2 b23 = *(const float2*)&Bsf[kk][2 * tx + 32];  // b64
      float a[8] = {a0.x, a0.y, a0.z, a0.w, a1.x, a1.y, a1.z, a1.w};
#pragma unroll
      for (int i = 0; i < 8; ++i) {
        acc[i][0] += a[i] * b01.x;  // fp32 fmac, k-ascending chain
        acc[i][1] += a[i] * b01.y;
        acc[i][2] += a[i] * b23.x;
        acc[i][3] += a[i] * b23.y;
      }
    }
    __syncthreads();
  }
#pragma unroll
  for (int i = 0; i < 8; ++i) {
    int mm = m0 + ty * 8 + i;
    size_t rowoff = (size_t)mm * N + n0;
#pragma unroll
    for (int half = 0; half < 2; ++half) {
      int nn = 2 * tx + half * 32;
      float2 o;
      o.x = silu_f(acc[i][half * 2 + 0]);
      o.y = silu_f(acc[i][half * 2 + 1]);
      *(float2*)&Cout[rowoff + nn] = o;
    }
  }
}

// ---------------- Kernel C: fp32 chain — byte-identical to R10..R12 ----------
__global__ __launch_bounds__(256) void conv_kernel(
    const float* __restrict__ x, const float* __restrict__ km,
    const float* __restrict__ fa, const float* __restrict__ pa,
    float* __restrict__ conv) {
  int l = blockIdx.x;
  int tid = threadIdx.x;
  __shared__ int s_idx[SDIM];
  __shared__ int s_ifl[SDIM];
  __shared__ float s_wc[SDIM];
  __shared__ float s_val[SDIM];
  __shared__ float kern[HDIM][SDIM];
  __shared__ float s_den[HDIM];
  if (tid < SDIM) {
    float f = fa[l], p = pa[l];
    float rel = __fadd_rn(__fmul_rn((float)(tid - HALF_SS), f), p);
    float pos = __fadd_rn((float)l, rel);
    bool valid = (pos >= 0.f) && (pos < (float)LDIM);
    int idx = (int)pos;                       // trunc toward zero
    idx = min(max(idx, 0), LDIM - 1);
    s_idx[tid] = idx;
    s_val[tid] = valid ? 1.f : 0.f;
    float np_ = __fdiv_rn(__fadd_rn(rel, MAXR), 2.f * MAXR);
    np_ = fminf(fmaxf(np_, 0.f), 1.f);
    float idxf = __fmul_rn(np_, (float)(KDIM - 1));
    int ifl = (int)idxf;
    ifl = min(max(ifl, 0), KDIM - 2);
    s_ifl[tid] = ifl;
    s_wc[tid] = __fsub_rn(idxf, (float)ifl);
  }
  __syncthreads();
  for (int t = tid; t < HDIM * SDIM; t += 256) {
    int h = t / SDIM, s = t - h * SDIM;
    const float* kb = km + (size_t)l * CDIM + h * KDIM;
    float wc = s_wc[s];
    float wf = __fsub_rn(1.f, wc);
    float v = __fadd_rn(__fmul_rn(kb[s_ifl[s]], wf), __fmul_rn(kb[s_ifl[s] + 1], wc));
    kern[h][s] = __fmul_rn(v, s_val[s]);
  }
  __syncthreads();
  if (tid < HDIM) {
    float sum = np_pairwise_sum(&kern[tid][0], SDIM);
    s_den[tid] = __fadd_rn(sum, 1e-8f);
  }
  __syncthreads();
  for (int t = tid; t < HDIM * SDIM; t += 256) {
    int h = t / SDIM, s = t - h * SDIM;
    kern[h][s] = __fdiv_rn(kern[h][s], s_den[h]);
  }
  __syncthreads();
  float acc[4] = {0.f, 0.f, 0.f, 0.f};
  for (int s = 0; s < SDIM; ++s) {
    const float* xr = x + (size_t)s_idx[s] * CDIM;
#pragma unroll
    for (int q = 0; q < 4; ++q) {
      int c = tid + q * 256;
      acc[q] = __fadd_rn(acc[q], __fmul_rn(xr[c], kern[c >> 6][s]));
    }
  }
#pragma unroll
  for (int q = 0; q < 4; ++q) {
    int c = tid + q * 256;
    conv[(size_t)l * CDIM + c] = acc[q];
  }
}

extern "C" void kernel_launch(void* const* d_in, const int* in_sizes, int n_in,
                              void* d_out, int out_size, void* d_ws, size_t ws_size,
                              hipStream_t stream) {
  const float* x  = (const float*)d_in[0];
  const float* Ww = (const float*)d_in[1];
  const float* bw = (const float*)d_in[2];
  const float* Wk = (const float*)d_in[3];
  const float* bk = (const float*)d_in[4];
  const float* Wo = (const float*)d_in[5];
  float* out = (float*)d_out;

  float* fa   = (float*)d_ws;
  float* pa   = fa + LDIM;
  float* km   = pa + LDIM;                   // 16 MB
  float* conv = km + (size_t)LDIM * CDIM;    // 16 MB

  wave_kernel<<<LDIM, 256, 0, stream>>>(x, Ww, bw, fa, pa);

  dim3 kmgrid(CDIM / 64, LDIM / 128);        // 16 x 32 = 512 blocks (2/CU)
  gemm_bt_silu_f64<<<kmgrid, 256, 0, stream>>>(x, Wk, bk, km, LDIM, CDIM, CDIM);

  conv_kernel<<<LDIM, 256, 0, stream>>>(x, km, fa, pa, conv);

  dim3 ogrid(CDIM / 64, LDIM / 128);         // 16 x 32 = 512 blocks (2/CU)
  gemm_bt_silu_f32<<<ogrid, 256, 0, stream>>>(conv, Wo, out, LDIM, CDIM, CDIM);
}

// Round 4
// 528.181 us; speedup vs baseline: 1.3177x; 1.0213x over previous
//
#include <hip/hip_runtime.h>
#include <math.h>

#define LDIM 4096
#define CDIM 1024
#define HDIM 16
#define KDIM 64
#define SDIM 33
#define HALF_SS 16
#define MAXF 16.0f
#define MINF 1.0f
#define MAXR 256.0f

// XOR row-swizzle: spreads the 8 kq-groups of a staging write 2-to-1 over all
// 32 banks (2-way = free), while keeping 4-element b128 read groups contiguous
// (XOR by a multiple of 4 maps aligned-4 blocks to aligned-4 blocks, and
// positions un-XOR to source rows in ascending order).
#define SW(k) ((((k) >> 2) & 7) << 2)

// 0.5-ulp predictors for np's fp32 transcendentals: fp64 op, one round to fp32.
__device__ __forceinline__ float sigmoid_np(float z) {
  float e = (float)exp(-(double)z);
  return __fdiv_rn(1.0f, __fadd_rn(1.0f, e));
}
__device__ __forceinline__ float silu_f(float z) {  // jax.nn order: z * sigmoid(z)
  return __fmul_rn(z, sigmoid_np(z));
}

// numpy pairwise-8 sum (8 <= n <= 128 path)
__device__ __forceinline__ float np_pairwise_sum(const float* a, int n) {
  float r[8];
#pragma unroll
  for (int j = 0; j < 8; ++j) r[j] = a[j];
  int i = 8;
  for (; i + 8 <= n; i += 8)
#pragma unroll
    for (int j = 0; j < 8; ++j) r[j] = __fadd_rn(r[j], a[i + j]);
  float res = __fadd_rn(__fadd_rn(__fadd_rn(r[0], r[1]), __fadd_rn(r[2], r[3])),
                        __fadd_rn(__fadd_rn(r[4], r[5]), __fadd_rn(r[6], r[7])));
  for (; i < n; ++i) res = __fadd_rn(res, a[i]);
  return res;
}

// ------- Kernel A: wave projection — fp64 dot (8-lane split) -> fp32 cast ----
__global__ __launch_bounds__(256) void wave_kernel(
    const float* __restrict__ x, const float* __restrict__ Ww,
    const float* __restrict__ bw, float* __restrict__ fa, float* __restrict__ pa) {
  __shared__ float xs[CDIM];
  __shared__ float wp[2 * HDIM];
  int l = blockIdx.x;
  int tid = threadIdx.x;
  const float* xrow = x + (size_t)l * CDIM;
  for (int c = tid; c < CDIM; c += 256) xs[c] = xrow[c];
  __syncthreads();
  int j = tid >> 3, sub = tid & 7;  // 32 outputs x 8 lanes, fp64 partials
  const float* wrow = Ww + j * CDIM;
  double acc = 0.0;
  for (int c = sub; c < CDIM; c += 8) acc += (double)xs[c] * (double)wrow[c];
  for (int off = 4; off; off >>= 1) acc += __shfl_down(acc, off, 8);
  if (sub == 0) {
    float v32 = (float)(acc + (double)bw[j]);  // single cast to fp32 (bw == 0)
    wp[j] = silu_f(v32);
  }
  __syncthreads();
  if (tid == 0) {
    float fv[HDIM], pv[HDIM];
    for (int h = 0; h < HDIM; ++h) {
      fv[h] = __fadd_rn(__fmul_rn(sigmoid_np(wp[h]), MAXF - MINF), MINF);
      float t32 = (float)tanh((double)wp[HDIM + h]);
      pv[h] = __fmul_rn(t32, MAXF);
    }
    fa[l] = __fdiv_rn(np_pairwise_sum(fv, HDIM), (float)HDIM);
    pa[l] = __fdiv_rn(np_pairwise_sum(pv, HDIM), (float)HDIM);
  }
}

// --- km GEMM: C = silu(fp32(A64 @ B64^T) + bias) ----------------------------
// 128x64 tile, 256 thr, acc 8x4 fp64, BK=32, single-buffered.
// KEY CHANGE vs R3: LDS staged as FLOAT (f32->f64 cvt AFTER the LDS read —
// lossless, so products/chains are bit-identical). This cuts DS reads from
// 6 b128 to 3 b128 per kk per thread (DS-issue was the measured limiter:
// 581 cy/kk observed vs 256 cy DP floor). XOR-4s swizzle makes staging
// writes 2-way (free) and keeps all reads b128-contiguous & conflict-free.
//   * A [k][128+4 fl]: read 2x b128 at (ty*8)^sw, (ty*8+4)^sw (4 uniq addrs
//     per wave, banks {0,8,16,24}+c -> conflict-free).
//   * B [k][64+4 fl]: cols {4tx..4tx+3} -> 1x b128, 16 uniq addrs, 2-way free.
//   * C-write: float4, coalesced.
__global__ __launch_bounds__(256) void gemm_bt_silu_f64(
    const float* __restrict__ A, const float* __restrict__ B,
    const float* __restrict__ bias, float* __restrict__ Cout,
    int M, int N, int Kd) {
  __shared__ float Asf[32][132];  // 16.9 KB  (row 528B = 33*16, b128-aligned)
  __shared__ float Bsf[32][68];   //  8.7 KB  (row 272B = 17*16)
  int tid = threadIdx.x;
  int tx = tid & 15;   // n-dir: cols 4tx..4tx+3
  int ty = tid >> 4;   // m-dir: rows ty*8..ty*8+7
  int m0 = blockIdx.y * 128, n0 = blockIdx.x * 64;
  double acc[8][4] = {};
  for (int kt = 0; kt < Kd; kt += 32) {
    // stage A: 128 rows x 32 k; 4 float4/thread, swizzled transpose
#pragma unroll
    for (int q = 0; q < 4; ++q) {
      int e = tid + 256 * q;
      int row = e >> 3, kq = (e & 7) * 4;
      int sw = SW(kq);             // same for kq..kq+3
      int rs = row ^ sw;
      float4 va = *(const float4*)(A + (size_t)(m0 + row) * Kd + kt + kq);
      Asf[kq + 0][rs] = va.x; Asf[kq + 1][rs] = va.y;
      Asf[kq + 2][rs] = va.z; Asf[kq + 3][rs] = va.w;
    }
    // stage B: 64 rows x 32 k; 2 float4/thread
#pragma unroll
    for (int q = 0; q < 2; ++q) {
      int e = tid + 256 * q;
      int row = e >> 3, kq = (e & 7) * 4;
      int sw = SW(kq);
      int rs = row ^ sw;
      float4 vb = *(const float4*)(B + (size_t)(n0 + row) * Kd + kt + kq);
      Bsf[kq + 0][rs] = vb.x; Bsf[kq + 1][rs] = vb.y;
      Bsf[kq + 2][rs] = vb.z; Bsf[kq + 3][rs] = vb.w;
    }
    __syncthreads();
#pragma unroll
    for (int kk = 0; kk < 32; ++kk) {
      int sw = SW(kk);
      float4 af0 = *(const float4*)&Asf[kk][(ty * 8) ^ sw];      // rows +0..3
      float4 af1 = *(const float4*)&Asf[kk][(ty * 8 + 4) ^ sw];  // rows +4..7
      float4 bf  = *(const float4*)&Bsf[kk][(tx * 4) ^ sw];      // cols 4tx..+3
      double ad[8] = {(double)af0.x, (double)af0.y, (double)af0.z, (double)af0.w,
                      (double)af1.x, (double)af1.y, (double)af1.z, (double)af1.w};
      double bd[4] = {(double)bf.x, (double)bf.y, (double)bf.z, (double)bf.w};
#pragma unroll
      for (int i = 0; i < 8; ++i)
#pragma unroll
        for (int j2 = 0; j2 < 4; ++j2) acc[i][j2] += ad[i] * bd[j2];  // v_fma_f64
    }
    __syncthreads();
  }
#pragma unroll
  for (int i = 0; i < 8; ++i) {
    int mm = m0 + ty * 8 + i;
    int nn = n0 + tx * 4;
    float4 o;
    float v;
    v = (float)acc[i][0]; v = __fadd_rn(v, bias[nn + 0]); o.x = silu_f(v);
    v = (float)acc[i][1]; v = __fadd_rn(v, bias[nn + 1]); o.y = silu_f(v);
    v = (float)acc[i][2]; v = __fadd_rn(v, bias[nn + 2]); o.z = silu_f(v);
    v = (float)acc[i][3]; v = __fadd_rn(v, bias[nn + 3]); o.w = silu_f(v);
    *(float4*)&Cout[(size_t)mm * N + nn] = o;
  }
}

// --- out GEMM: fp32 accumulate; 128x128 tile, 8x8 acc/thread, BK=32 ---------
// Restores R0's winning shape (16 FMA per DS-instr; R3's 128x64 regressed it)
// and adds the swizzled staging + b128-only reads. Per-output k-order
// identical (sequential fmac chain, k ascending).
__global__ __launch_bounds__(256) void gemm_bt_silu_f32(
    const float* __restrict__ A, const float* __restrict__ B,
    float* __restrict__ Cout, int M, int N, int Kd) {
  __shared__ float Asf[32][132];  // 16.9 KB
  __shared__ float Bsf[32][132];  // 16.9 KB
  int tid = threadIdx.x;
  int tx = tid & 15;   // n-dir: cols 8tx..8tx+7
  int ty = tid >> 4;   // m-dir: rows ty*8..ty*8+7
  int m0 = blockIdx.y * 128, n0 = blockIdx.x * 128;
  float acc[8][8] = {};
  for (int kt = 0; kt < Kd; kt += 32) {
    // stage A and B: each 128 rows x 32 k; 4 float4/thread each
#pragma unroll
    for (int q = 0; q < 4; ++q) {
      int e = tid + 256 * q;
      int row = e >> 3, kq = (e & 7) * 4;
      int sw = SW(kq);
      int rs = row ^ sw;
      float4 va = *(const float4*)(A + (size_t)(m0 + row) * Kd + kt + kq);
      Asf[kq + 0][rs] = va.x; Asf[kq + 1][rs] = va.y;
      Asf[kq + 2][rs] = va.z; Asf[kq + 3][rs] = va.w;
      float4 vb = *(const float4*)(B + (size_t)(n0 + row) * Kd + kt + kq);
      Bsf[kq + 0][rs] = vb.x; Bsf[kq + 1][rs] = vb.y;
      Bsf[kq + 2][rs] = vb.z; Bsf[kq + 3][rs] = vb.w;
    }
    __syncthreads();
#pragma unroll
    for (int kk = 0; kk < 32; ++kk) {
      int sw = SW(kk);
      float4 a0 = *(const float4*)&Asf[kk][(ty * 8) ^ sw];
      float4 a1 = *(const float4*)&Asf[kk][(ty * 8 + 4) ^ sw];
      float4 b0 = *(const float4*)&Bsf[kk][(tx * 8) ^ sw];
      float4 b1 = *(const float4*)&Bsf[kk][(tx * 8 + 4) ^ sw];
      float a[8] = {a0.x, a0.y, a0.z, a0.w, a1.x, a1.y, a1.z, a1.w};
      float b[8] = {b0.x, b0.y, b0.z, b0.w, b1.x, b1.y, b1.z, b1.w};
#pragma unroll
      for (int i = 0; i < 8; ++i)
#pragma unroll
        for (int j2 = 0; j2 < 8; ++j2) acc[i][j2] += a[i] * b[j2];  // fp32 fmac
    }
    __syncthreads();
  }
#pragma unroll
  for (int i = 0; i < 8; ++i) {
    int mm = m0 + ty * 8 + i;
    int nn = n0 + tx * 8;
    float4 o0, o1;
    o0.x = silu_f(acc[i][0]); o0.y = silu_f(acc[i][1]);
    o0.z = silu_f(acc[i][2]); o0.w = silu_f(acc[i][3]);
    o1.x = silu_f(acc[i][4]); o1.y = silu_f(acc[i][5]);
    o1.z = silu_f(acc[i][6]); o1.w = silu_f(acc[i][7]);
    *(float4*)&Cout[(size_t)mm * N + nn] = o0;
    *(float4*)&Cout[(size_t)mm * N + nn + 4] = o1;
  }
}

// ---------------- Kernel C: fp32 chain — byte-identical to R10..R12 ----------
__global__ __launch_bounds__(256) void conv_kernel(
    const float* __restrict__ x, const float* __restrict__ km,
    const float* __restrict__ fa, const float* __restrict__ pa,
    float* __restrict__ conv) {
  int l = blockIdx.x;
  int tid = threadIdx.x;
  __shared__ int s_idx[SDIM];
  __shared__ int s_ifl[SDIM];
  __shared__ float s_wc[SDIM];
  __shared__ float s_val[SDIM];
  __shared__ float kern[HDIM][SDIM];
  __shared__ float s_den[HDIM];
  if (tid < SDIM) {
    float f = fa[l], p = pa[l];
    float rel = __fadd_rn(__fmul_rn((float)(tid - HALF_SS), f), p);
    float pos = __fadd_rn((float)l, rel);
    bool valid = (pos >= 0.f) && (pos < (float)LDIM);
    int idx = (int)pos;                       // trunc toward zero
    idx = min(max(idx, 0), LDIM - 1);
    s_idx[tid] = idx;
    s_val[tid] = valid ? 1.f : 0.f;
    float np_ = __fdiv_rn(__fadd_rn(rel, MAXR), 2.f * MAXR);
    np_ = fminf(fmaxf(np_, 0.f), 1.f);
    float idxf = __fmul_rn(np_, (float)(KDIM - 1));
    int ifl = (int)idxf;
    ifl = min(max(ifl, 0), KDIM - 2);
    s_ifl[tid] = ifl;
    s_wc[tid] = __fsub_rn(idxf, (float)ifl);
  }
  __syncthreads();
  for (int t = tid; t < HDIM * SDIM; t += 256) {
    int h = t / SDIM, s = t - h * SDIM;
    const float* kb = km + (size_t)l * CDIM + h * KDIM;
    float wc = s_wc[s];
    float wf = __fsub_rn(1.f, wc);
    float v = __fadd_rn(__fmul_rn(kb[s_ifl[s]], wf), __fmul_rn(kb[s_ifl[s] + 1], wc));
    kern[h][s] = __fmul_rn(v, s_val[s]);
  }
  __syncthreads();
  if (tid < HDIM) {
    float sum = np_pairwise_sum(&kern[tid][0], SDIM);
    s_den[tid] = __fadd_rn(sum, 1e-8f);
  }
  __syncthreads();
  for (int t = tid; t < HDIM * SDIM; t += 256) {
    int h = t / SDIM, s = t - h * SDIM;
    kern[h][s] = __fdiv_rn(kern[h][s], s_den[h]);
  }
  __syncthreads();
  float acc[4] = {0.f, 0.f, 0.f, 0.f};
  for (int s = 0; s < SDIM; ++s) {
    const float* xr = x + (size_t)s_idx[s] * CDIM;
#pragma unroll
    for (int q = 0; q < 4; ++q) {
      int c = tid + q * 256;
      acc[q] = __fadd_rn(acc[q], __fmul_rn(xr[c], kern[c >> 6][s]));
    }
  }
#pragma unroll
  for (int q = 0; q < 4; ++q) {
    int c = tid + q * 256;
    conv[(size_t)l * CDIM + c] = acc[q];
  }
}

extern "C" void kernel_launch(void* const* d_in, const int* in_sizes, int n_in,
                              void* d_out, int out_size, void* d_ws, size_t ws_size,
                              hipStream_t stream) {
  const float* x  = (const float*)d_in[0];
  const float* Ww = (const float*)d_in[1];
  const float* bw = (const float*)d_in[2];
  const float* Wk = (const float*)d_in[3];
  const float* bk = (const float*)d_in[4];
  const float* Wo = (const float*)d_in[5];
  float* out = (float*)d_out;

  float* fa   = (float*)d_ws;
  float* pa   = fa + LDIM;
  float* km   = pa + LDIM;                   // 16 MB
  float* conv = km + (size_t)LDIM * CDIM;    // 16 MB

  wave_kernel<<<LDIM, 256, 0, stream>>>(x, Ww, bw, fa, pa);

  dim3 kmgrid(CDIM / 64, LDIM / 128);        // 16 x 32 = 512 blocks (2/CU)
  gemm_bt_silu_f64<<<kmgrid, 256, 0, stream>>>(x, Wk, bk, km, LDIM, CDIM, CDIM);

  conv_kernel<<<LDIM, 256, 0, stream>>>(x, km, fa, pa, conv);

  dim3 ogrid(CDIM / 128, LDIM / 128);        // 8 x 32 = 256 blocks
  gemm_bt_silu_f32<<<ogrid, 256, 0, stream>>>(conv, Wo, out, LDIM, CDIM, CDIM);
}

// Round 7
// 456.133 us; speedup vs baseline: 1.5258x; 1.1580x over previous
//
#include <hip/hip_runtime.h>
#include <math.h>

#define LDIM 4096
#define CDIM 1024
#define HDIM 16
#define KDIM 64
#define SDIM 33
#define HALF_SS 16
#define MAXF 16.0f
#define MINF 1.0f
#define MAXR 256.0f

typedef double d4 __attribute__((ext_vector_type(4)));

#define MFMA_F64 __builtin_amdgcn_mfma_f64_16x16x4f64

// 0.5-ulp predictors for np's fp32 transcendentals: fp64 op, one round to fp32.
__device__ __forceinline__ float sigmoid_np(float z) {
  float e = (float)exp(-(double)z);
  return __fdiv_rn(1.0f, __fadd_rn(1.0f, e));
}
__device__ __forceinline__ float silu_f(float z) {  // jax.nn order: z * sigmoid(z)
  return __fmul_rn(z, sigmoid_np(z));
}

// numpy pairwise-8 sum (8 <= n <= 128 path)
__device__ __forceinline__ float np_pairwise_sum(const float* a, int n) {
  float r[8];
#pragma unroll
  for (int j = 0; j < 8; ++j) r[j] = a[j];
  int i = 8;
  for (; i + 8 <= n; i += 8)
#pragma unroll
    for (int j = 0; j < 8; ++j) r[j] = __fadd_rn(r[j], a[i + j]);
  float res = __fadd_rn(__fadd_rn(__fadd_rn(r[0], r[1]), __fadd_rn(r[2], r[3])),
                        __fadd_rn(__fadd_rn(r[4], r[5]), __fadd_rn(r[6], r[7])));
  for (; i < n; ++i) res = __fadd_rn(res, a[i]);
  return res;
}

// ------- Kernel A: wave projection — fp64 dot (8-lane split) -> fp32 cast ----
__global__ __launch_bounds__(256) void wave_kernel(
    const float* __restrict__ x, const float* __restrict__ Ww,
    const float* __restrict__ bw, float* __restrict__ fa, float* __restrict__ pa) {
  __shared__ float xs[CDIM];
  __shared__ float wp[2 * HDIM];
  int l = blockIdx.x;
  int tid = threadIdx.x;
  const float* xrow = x + (size_t)l * CDIM;
  for (int c = tid; c < CDIM; c += 256) xs[c] = xrow[c];
  __syncthreads();
  int j = tid >> 3, sub = tid & 7;  // 32 outputs x 8 lanes, fp64 partials
  const float* wrow = Ww + j * CDIM;
  double acc = 0.0;
  for (int c = sub; c < CDIM; c += 8) acc += (double)xs[c] * (double)wrow[c];
  for (int off = 4; off; off >>= 1) acc += __shfl_down(acc, off, 8);
  if (sub == 0) {
    float v32 = (float)(acc + (double)bw[j]);  // single cast to fp32 (bw == 0)
    wp[j] = silu_f(v32);
  }
  __syncthreads();
  if (tid == 0) {
    float fv[HDIM], pv[HDIM];
    for (int h = 0; h < HDIM; ++h) {
      fv[h] = __fadd_rn(__fmul_rn(sigmoid_np(wp[h]), MAXF - MINF), MINF);
      float t32 = (float)tanh((double)wp[HDIM + h]);
      pv[h] = __fmul_rn(t32, MAXF);
    }
    fa[l] = __fdiv_rn(np_pairwise_sum(fv, HDIM), (float)HDIM);
    pa[l] = __fdiv_rn(np_pairwise_sum(pv, HDIM), (float)HDIM);
  }
}

// --- km GEMM via v_mfma_f64_16x16x4 with runtime layout probe ---------------
// C = silu(fp32(A @ B^T) + bias), fp64 accumulate in AGPRs, one fp32 cast.
// R6 failed with the documented gfx90a layouts -> f64 MFMA layout on gfx950
// evidently deviates (the loop's "C/D dtype-independent" claim was verified
// only for 32-bit-accum types). Fix: self-decode at runtime.
//   Probe 1: mfma(lane_id, 1, 0)  -> each D element (i,j) = S_A(i) = sum of
//            the 4 lane-ids feeding A-row i. Decodes the ROW each (lane,reg)
//            holds, for ANY D permutation.
//   Probe 2: mfma(1, lane_id, 0)  -> decodes the COLUMN the same way.
//   A/B feed family is also identified from the probe sums:
//     lane = idx + 16k -> S = 4*idx + 96  (== 0 mod 4)
//     lane = 4*idx + k -> S = 16*idx + 6  (== 2 mod 4)   (disjoint sets)
// Tile: 128x64, 256 thr = 4 waves; wave w owns n-subtile w; 8 m-subtiles.
// LDS staged as FLOAT (lossless cvt after read), k-permuted col p=(k&3)*8+(k>>2)
// so one ds_read_b128 covers 4 k4-steps. Pitch 36 -> reads/writes <=2-way.
__global__ __launch_bounds__(256) void gemm_bt_silu_f64(
    const float* __restrict__ A, const float* __restrict__ B,
    const float* __restrict__ bias, float* __restrict__ Cout,
    int M, int N, int Kd) {
  __shared__ float Asf[128][36];  // 18.4 KB
  __shared__ float Bsf[64][36];   //  9.2 KB
  int tid = threadIdx.x;
  int w  = tid >> 6;   // wave -> n-subtile
  int l  = tid & 63;
  int m0 = blockIdx.y * 128, n0 = blockIdx.x * 64;

  // ---- layout probe (2 MFMAs, once per thread) ----
  d4 zv = (d4)(0.0);
  double lane_d = (double)l;
  d4 pA = MFMA_F64(lane_d, 1.0, zv, 0, 0, 0);  // pA[r] = S_A(row of this reg)
  d4 pB = MFMA_F64(1.0, lane_d, zv, 0, 0, 0);  // pB[r] = S_B(col of this reg)
  int sa0 = (int)pA[0], sb0 = (int)pB[0];
  bool aH1 = ((sa0 & 3) == 0);
  bool bH1 = ((sb0 & 3) == 0);
  int lmA = aH1 ? (l & 15) : (l >> 2);   // A row this lane feeds
  int lqA = aH1 ? (l >> 4) : (l & 3);    // A k-residue this lane feeds
  int lmB = bH1 ? (l & 15) : (l >> 2);   // B col this lane feeds
  int lqB = bH1 ? (l >> 4) : (l & 3);    // B k-residue
  int di[4], dj[4];
#pragma unroll
  for (int r = 0; r < 4; ++r) {
    int va = (int)pA[r], vb = (int)pB[r];
    di[r] = (aH1 ? ((va - 96) >> 2) : ((va - 6) >> 4)) & 15;  // D row (m-sub)
    dj[r] = (bH1 ? ((vb - 96) >> 2) : ((vb - 6) >> 4)) & 15;  // D col (n-sub)
  }

  d4 acc[8];
#pragma unroll
  for (int i = 0; i < 8; ++i) acc[i] = (d4)(0.0);

  for (int kt = 0; kt < Kd; kt += 32) {
    // stage A: 128 rows x 32 k -> [row][p]; 4 float4/thread
#pragma unroll
    for (int qi = 0; qi < 4; ++qi) {
      int e = tid + 256 * qi;
      int row = e >> 3, j = e & 7;  // global k = kt + 4j .. 4j+3
      float4 v = *(const float4*)(A + (size_t)(m0 + row) * Kd + kt + 4 * j);
      Asf[row][j] = v.x; Asf[row][j + 8] = v.y;
      Asf[row][j + 16] = v.z; Asf[row][j + 24] = v.w;
    }
    // stage B: 64 rows x 32 k; 2 float4/thread
#pragma unroll
    for (int qi = 0; qi < 2; ++qi) {
      int e = tid + 256 * qi;
      int row = e >> 3, j = e & 7;
      float4 v = *(const float4*)(B + (size_t)(n0 + row) * Kd + kt + 4 * j);
      Bsf[row][j] = v.x; Bsf[row][j + 8] = v.y;
      Bsf[row][j + 16] = v.z; Bsf[row][j + 24] = v.w;
    }
    __syncthreads();
#pragma unroll
    for (int t = 0; t < 2; ++t) {
      // one b128 per fragment covers 4 k4-steps (p = 8*lq + 4t .. +3)
      float4 bv = *(const float4*)&Bsf[16 * w + lmB][8 * lqB + 4 * t];
      float4 av0 = *(const float4*)&Asf[lmA][8 * lqA + 4 * t];
      float4 av1 = *(const float4*)&Asf[16 + lmA][8 * lqA + 4 * t];
      float4 av2 = *(const float4*)&Asf[32 + lmA][8 * lqA + 4 * t];
      float4 av3 = *(const float4*)&Asf[48 + lmA][8 * lqA + 4 * t];
      float4 av4 = *(const float4*)&Asf[64 + lmA][8 * lqA + 4 * t];
      float4 av5 = *(const float4*)&Asf[80 + lmA][8 * lqA + 4 * t];
      float4 av6 = *(const float4*)&Asf[96 + lmA][8 * lqA + 4 * t];
      float4 av7 = *(const float4*)&Asf[112 + lmA][8 * lqA + 4 * t];
      float bs[4] = {bv.x, bv.y, bv.z, bv.w};
      float as0[4] = {av0.x, av0.y, av0.z, av0.w};
      float as1[4] = {av1.x, av1.y, av1.z, av1.w};
      float as2[4] = {av2.x, av2.y, av2.z, av2.w};
      float as3[4] = {av3.x, av3.y, av3.z, av3.w};
      float as4[4] = {av4.x, av4.y, av4.z, av4.w};
      float as5[4] = {av5.x, av5.y, av5.z, av5.w};
      float as6[4] = {av6.x, av6.y, av6.z, av6.w};
      float as7[4] = {av7.x, av7.y, av7.z, av7.w};
#pragma unroll
      for (int s = 0; s < 4; ++s) {  // step covers k = kt + 4*(4t+s) + lq
        double bd = (double)bs[s];
        acc[0] = MFMA_F64((double)as0[s], bd, acc[0], 0, 0, 0);
        acc[1] = MFMA_F64((double)as1[s], bd, acc[1], 0, 0, 0);
        acc[2] = MFMA_F64((double)as2[s], bd, acc[2], 0, 0, 0);
        acc[3] = MFMA_F64((double)as3[s], bd, acc[3], 0, 0, 0);
        acc[4] = MFMA_F64((double)as4[s], bd, acc[4], 0, 0, 0);
        acc[5] = MFMA_F64((double)as5[s], bd, acc[5], 0, 0, 0);
        acc[6] = MFMA_F64((double)as6[s], bd, acc[6], 0, 0, 0);
        acc[7] = MFMA_F64((double)as7[s], bd, acc[7], 0, 0, 0);
      }
    }
    __syncthreads();
  }

  // D write via probe-decoded coordinates (valid for any D permutation)
#pragma unroll
  for (int mt = 0; mt < 8; ++mt) {
#pragma unroll
    for (int r = 0; r < 4; ++r) {
      int mm = m0 + 16 * mt + di[r];
      int nn = n0 + 16 * w + dj[r];
      float v32 = (float)acc[mt][r];      // fp64 dot -> one fp32 cast
      v32 = __fadd_rn(v32, bias[nn]);     // bias == 0
      Cout[(size_t)mm * N + nn] = silu_f(v32);
    }
  }
}

// --- out GEMM: fp32 accumulate; 128x128 tile, 8x8 acc/thread ----------------
// R0 version verbatim (verified). Per-element k-order: sequential fmac chain.
__global__ __launch_bounds__(256) void gemm_bt_silu_f32(
    const float* __restrict__ A, const float* __restrict__ B,
    float* __restrict__ Cout, int M, int N, int Kd) {
  __shared__ float Asf[16][128];
  __shared__ float Bsf[16][128];
  int tid = threadIdx.x;
  int tx = tid & 15, ty = tid >> 4;
  int m0 = blockIdx.y * 128, n0 = blockIdx.x * 128;
  float acc[8][8] = {};
  for (int kt = 0; kt < Kd; kt += 16) {
#pragma unroll
    for (int q = 0; q < 2; ++q) {
      int e = tid + 256 * q;
      int row = e >> 2, kq = (e & 3) * 4;
      float4 va = *(const float4*)(A + (size_t)(m0 + row) * Kd + kt + kq);
      Asf[kq + 0][row] = va.x; Asf[kq + 1][row] = va.y;
      Asf[kq + 2][row] = va.z; Asf[kq + 3][row] = va.w;
      float4 vb = *(const float4*)(B + (size_t)(n0 + row) * Kd + kt + kq);
      Bsf[kq + 0][row] = vb.x; Bsf[kq + 1][row] = vb.y;
      Bsf[kq + 2][row] = vb.z; Bsf[kq + 3][row] = vb.w;
    }
    __syncthreads();
#pragma unroll
    for (int kk = 0; kk < 16; ++kk) {
      float4 a0 = *(const float4*)&Asf[kk][ty * 8];
      float4 a1 = *(const float4*)&Asf[kk][ty * 8 + 4];
      float4 b0 = *(const float4*)&Bsf[kk][tx * 8];
      float4 b1 = *(const float4*)&Bsf[kk][tx * 8 + 4];
      float a[8] = {a0.x, a0.y, a0.z, a0.w, a1.x, a1.y, a1.z, a1.w};
      float b[8] = {b0.x, b0.y, b0.z, b0.w, b1.x, b1.y, b1.z, b1.w};
#pragma unroll
      for (int i = 0; i < 8; ++i)
#pragma unroll
        for (int j2 = 0; j2 < 8; ++j2) acc[i][j2] += a[i] * b[j2];  // fp32 fmac
    }
    __syncthreads();
  }
#pragma unroll
  for (int i = 0; i < 8; ++i) {
    int mm = m0 + ty * 8 + i;
#pragma unroll
    for (int j2 = 0; j2 < 8; ++j2) {
      int nn = n0 + tx * 8 + j2;
      Cout[(size_t)mm * N + nn] = silu_f(acc[i][j2]);
    }
  }
}

// ---------------- Kernel C: fp32 chain — byte-identical to R10..R12 ----------
__global__ __launch_bounds__(256) void conv_kernel(
    const float* __restrict__ x, const float* __restrict__ km,
    const float* __restrict__ fa, const float* __restrict__ pa,
    float* __restrict__ conv) {
  int l = blockIdx.x;
  int tid = threadIdx.x;
  __shared__ int s_idx[SDIM];
  __shared__ int s_ifl[SDIM];
  __shared__ float s_wc[SDIM];
  __shared__ float s_val[SDIM];
  __shared__ float kern[HDIM][SDIM];
  __shared__ float s_den[HDIM];
  if (tid < SDIM) {
    float f = fa[l], p = pa[l];
    float rel = __fadd_rn(__fmul_rn((float)(tid - HALF_SS), f), p);
    float pos = __fadd_rn((float)l, rel);
    bool valid = (pos >= 0.f) && (pos < (float)LDIM);
    int idx = (int)pos;                       // trunc toward zero
    idx = min(max(idx, 0), LDIM - 1);
    s_idx[tid] = idx;
    s_val[tid] = valid ? 1.f : 0.f;
    float np_ = __fdiv_rn(__fadd_rn(rel, MAXR), 2.f * MAXR);
    np_ = fminf(fmaxf(np_, 0.f), 1.f);
    float idxf = __fmul_rn(np_, (float)(KDIM - 1));
    int ifl = (int)idxf;
    ifl = min(max(ifl, 0), KDIM - 2);
    s_ifl[tid] = ifl;
    s_wc[tid] = __fsub_rn(idxf, (float)ifl);
  }
  __syncthreads();
  for (int t = tid; t < HDIM * SDIM; t += 256) {
    int h = t / SDIM, s = t - h * SDIM;
    const float* kb = km + (size_t)l * CDIM + h * KDIM;
    float wc = s_wc[s];
    float wf = __fsub_rn(1.f, wc);
    float v = __fadd_rn(__fmul_rn(kb[s_ifl[s]], wf), __fmul_rn(kb[s_ifl[s] + 1], wc));
    kern[h][s] = __fmul_rn(v, s_val[s]);
  }
  __syncthreads();
  if (tid < HDIM) {
    float sum = np_pairwise_sum(&kern[tid][0], SDIM);
    s_den[tid] = __fadd_rn(sum, 1e-8f);
  }
  __syncthreads();
  for (int t = tid; t < HDIM * SDIM; t += 256) {
    int h = t / SDIM, s = t - h * SDIM;
    kern[h][s] = __fdiv_rn(kern[h][s], s_den[h]);
  }
  __syncthreads();
  float acc[4] = {0.f, 0.f, 0.f, 0.f};
  for (int s = 0; s < SDIM; ++s) {
    const float* xr = x + (size_t)s_idx[s] * CDIM;
#pragma unroll
    for (int q = 0; q < 4; ++q) {
      int c = tid + q * 256;
      acc[q] = __fadd_rn(acc[q], __fmul_rn(xr[c], kern[c >> 6][s]));
    }
  }
#pragma unroll
  for (int q = 0; q < 4; ++q) {
    int c = tid + q * 256;
    conv[(size_t)l * CDIM + c] = acc[q];
  }
}

extern "C" void kernel_launch(void* const* d_in, const int* in_sizes, int n_in,
                              void* d_out, int out_size, void* d_ws, size_t ws_size,
                              hipStream_t stream) {
  const float* x  = (const float*)d_in[0];
  const float* Ww = (const float*)d_in[1];
  const float* bw = (const float*)d_in[2];
  const float* Wk = (const float*)d_in[3];
  const float* bk = (const float*)d_in[4];
  const float* Wo = (const float*)d_in[5];
  float* out = (float*)d_out;

  float* fa   = (float*)d_ws;
  float* pa   = fa + LDIM;
  float* km   = pa + LDIM;                   // 16 MB
  float* conv = km + (size_t)LDIM * CDIM;    // 16 MB

  wave_kernel<<<LDIM, 256, 0, stream>>>(x, Ww, bw, fa, pa);

  dim3 kmgrid(CDIM / 64, LDIM / 128);        // 16 x 32 = 512 blocks (2/CU)
  gemm_bt_silu_f64<<<kmgrid, 256, 0, stream>>>(x, Wk, bk, km, LDIM, CDIM, CDIM);

  conv_kernel<<<LDIM, 256, 0, stream>>>(x, km, fa, pa, conv);

  dim3 ogrid(CDIM / 128, LDIM / 128);        // 8 x 32 = 256 blocks
  gemm_bt_silu_f32<<<ogrid, 256, 0, stream>>>(conv, Wo, out, LDIM, CDIM, CDIM);
}